// Round 1
// baseline (136.259 us; speedup 1.0000x reference)
//
#include <hip/hip_runtime.h>

#define N_FEAT 1024
#define N_LAYER 4
#define R 2  // rows per wave: small register footprint -> 4 waves/SIMD

// Algebra: xi = A_i*x0 + C_i, C_i = sum_{j<i} b_j (row-independent).
//   p_i = <x0,w_i>  (independent dots), e_i = <C_i,w_i> (row-independent),
//   A_{i+1} = A_i + A_i*p_i + e_i ; out = A_4*x0 + C_4.
// R=2 keeps per-thread live state ~90 VGPRs (x0: 8 float4 = 32, p: 8,
// transients ~40) so __launch_bounds__(256,4) holds 4 waves/SIMD without
// spilling. csum is NOT carried across the kernel: the epilogue reloads the
// biases (32 KB total, L1/L2-hot after the main loop) and re-sums -> 16 fewer
// live VGPRs. Weights amortize only 2x per wave now, but weight traffic is
// cache-resident and hidden behind the 128 MiB HBM stream.
__global__ __launch_bounds__(256, 4) void crossnet_kernel(
    const float* __restrict__ x,
    const float* __restrict__ weight_w,
    const float* __restrict__ weight_b,
    float* __restrict__ out,
    int n_rows) {
  const int wave = threadIdx.x >> 6;
  const int lane = threadIdx.x & 63;
  const int row0 = (blockIdx.x * 4 + wave) * R;
  if (row0 >= n_rows) return;

  const float4* xq = (const float4*)x;   // row stride = 256 float4
  float4* oq = (float4*)out;

  // ---- issue all x loads first: 8 independent 16B/lane HBM loads ----
  float4 x0[R * 4];
#pragma unroll
  for (int r = 0; r < R; ++r)
#pragma unroll
    for (int c = 0; c < 4; ++c)
      x0[r * 4 + c] = xq[(size_t)(row0 + r) * 256 + c * 64 + lane];

  float p[R * N_LAYER];
#pragma unroll
  for (int k = 0; k < R * N_LAYER; ++k) p[k] = 0.f;
  float e[N_LAYER] = {0.f, 0.f, 0.f, 0.f};

  // ---- per-chunk: load w/b (L1/L2-hot), accumulate partials ----
#pragma unroll
  for (int c = 0; c < 4; ++c) {
    float4 w[N_LAYER];
#pragma unroll
    for (int i = 0; i < N_LAYER; ++i)
      w[i] = ((const float4*)(weight_w + i * N_FEAT))[c * 64 + lane];

    float4 cum = make_float4(0.f, 0.f, 0.f, 0.f);
#pragma unroll
    for (int i = 0; i < N_LAYER; ++i) {
      if (i > 0)
        e[i] += cum.x * w[i].x + cum.y * w[i].y + cum.z * w[i].z + cum.w * w[i].w;
      float4 b = ((const float4*)(weight_b + i * N_FEAT))[c * 64 + lane];
      cum.x += b.x; cum.y += b.y; cum.z += b.z; cum.w += b.w;
    }

#pragma unroll
    for (int r = 0; r < R; ++r) {
      const float4 xv = x0[r * 4 + c];
#pragma unroll
      for (int i = 0; i < N_LAYER; ++i) {
        p[r * N_LAYER + i] += xv.x * w[i].x + xv.y * w[i].y +
                              xv.z * w[i].z + xv.w * w[i].w;
      }
    }
  }

  // ---- one butterfly phase: 11 independent values, 6 steps ----
#pragma unroll
  for (int off = 32; off > 0; off >>= 1) {
#pragma unroll
    for (int k = 0; k < R * N_LAYER; ++k) p[k] += __shfl_xor(p[k], off, 64);
#pragma unroll
    for (int i = 1; i < N_LAYER; ++i) e[i] += __shfl_xor(e[i], off, 64);
  }

  // ---- per-row scalar recurrence ----
  float A[R];
#pragma unroll
  for (int r = 0; r < R; ++r) {
    A[r] = 1.f;
#pragma unroll
    for (int i = 0; i < N_LAYER; ++i)
      A[r] += A[r] * p[r * N_LAYER + i] + e[i];
  }

  // ---- epilogue: recompute csum from L1-hot biases, streaming store ----
#pragma unroll
  for (int c = 0; c < 4; ++c) {
    float4 cum = make_float4(0.f, 0.f, 0.f, 0.f);
#pragma unroll
    for (int i = 0; i < N_LAYER; ++i) {
      float4 b = ((const float4*)(weight_b + i * N_FEAT))[c * 64 + lane];
      cum.x += b.x; cum.y += b.y; cum.z += b.z; cum.w += b.w;
    }
#pragma unroll
    for (int r = 0; r < R; ++r) {
      const float4 xv = x0[r * 4 + c];
      float4 o;
      o.x = fmaf(xv.x, A[r], cum.x);
      o.y = fmaf(xv.y, A[r], cum.y);
      o.z = fmaf(xv.z, A[r], cum.z);
      o.w = fmaf(xv.w, A[r], cum.w);
      oq[(size_t)(row0 + r) * 256 + c * 64 + lane] = o;
    }
  }
}

extern "C" void kernel_launch(void* const* d_in, const int* in_sizes, int n_in,
                              void* d_out, int out_size, void* d_ws, size_t ws_size,
                              hipStream_t stream) {
  const float* x = (const float*)d_in[0];
  const float* ww = (const float*)d_in[1];
  const float* wb = (const float*)d_in[2];
  float* out = (float*)d_out;

  int n_rows = in_sizes[0] / N_FEAT;                 // 16384
  int rows_per_block = 4 * R;                        // 4 waves x 2 rows = 8
  int n_blocks = (n_rows + rows_per_block - 1) / rows_per_block;  // 2048
  crossnet_kernel<<<n_blocks, 256, 0, stream>>>(x, ww, wb, out, n_rows);
}

// Round 2
// 132.491 us; speedup vs baseline: 1.0284x; 1.0284x over previous
//
#include <hip/hip_runtime.h>

#define N_FEAT 1024
#define N_LAYER 4
#define R1 8  // rows per wave in phase 1: keeps w/b reads amortized 8x (R=2 regressed)

// Algebra: xi = A_i*x0 + C_i with C_i = sum_{j<i} b_j (row-independent).
//   p_i = <x0,w_i>, e_i = <C_i,w_i> (row-independent),
//   A_{i+1} = A_i + A_i*p_i + e_i ; out = A_4*x0 + csum, csum = sum_j b_j.
//
// Two-pass split: a single-pass kernel must hold x0 in VGPRs across the
// reduction (128 VGPRs -> 8 waves/CU, BW idles in compute/store phases).
// Phase 1 streams x once for the dots and writes only A[n_rows] (+csum) to
// workspace; phase 2 is a pure elementwise stream (x is L3-hot after ph1).

__global__ __launch_bounds__(256) void crossnet_phase1(
    const float* __restrict__ x,
    const float* __restrict__ weight_w,
    const float* __restrict__ weight_b,
    float* __restrict__ A_out,      // [n_rows]
    float* __restrict__ csum_out,   // [N_FEAT]
    int n_rows) {
  const int wave = threadIdx.x >> 6;
  const int lane = threadIdx.x & 63;
  const int row0 = (blockIdx.x * 4 + wave) * R1;

  // Block 0 additionally materializes csum = sum_i b_i (256 threads x 1 float4).
  if (blockIdx.x == 0) {
    const int t = threadIdx.x;  // float4 index 0..255
    float4 c = make_float4(0.f, 0.f, 0.f, 0.f);
#pragma unroll
    for (int i = 0; i < N_LAYER; ++i) {
      const float4 b = ((const float4*)(weight_b + i * N_FEAT))[t];
      c.x += b.x; c.y += b.y; c.z += b.z; c.w += b.w;
    }
    ((float4*)csum_out)[t] = c;
  }

  if (row0 >= n_rows) return;

  const float4* xq = (const float4*)x;  // row stride = 256 float4

  float p[R1 * N_LAYER];
#pragma unroll
  for (int k = 0; k < R1 * N_LAYER; ++k) p[k] = 0.f;
  float e[N_LAYER] = {0.f, 0.f, 0.f, 0.f};

  // ---- per-chunk: load w/b (L1/L2-hot), stream x, accumulate partials ----
#pragma unroll
  for (int c = 0; c < 4; ++c) {
    float4 w[N_LAYER];
#pragma unroll
    for (int i = 0; i < N_LAYER; ++i)
      w[i] = ((const float4*)(weight_w + i * N_FEAT))[c * 64 + lane];

    float4 cum = make_float4(0.f, 0.f, 0.f, 0.f);
#pragma unroll
    for (int i = 0; i < N_LAYER; ++i) {
      if (i > 0)
        e[i] += cum.x * w[i].x + cum.y * w[i].y + cum.z * w[i].z + cum.w * w[i].w;
      const float4 b = ((const float4*)(weight_b + i * N_FEAT))[c * 64 + lane];
      cum.x += b.x; cum.y += b.y; cum.z += b.z; cum.w += b.w;
    }

#pragma unroll
    for (int r = 0; r < R1; ++r) {
      const float4 xv = xq[(size_t)(row0 + r) * 256 + c * 64 + lane];
#pragma unroll
      for (int i = 0; i < N_LAYER; ++i) {
        p[r * N_LAYER + i] += xv.x * w[i].x + xv.y * w[i].y +
                              xv.z * w[i].z + xv.w * w[i].w;
      }
    }
  }

  // ---- one butterfly phase: 35 independent values, 6 steps ----
#pragma unroll
  for (int off = 32; off > 0; off >>= 1) {
#pragma unroll
    for (int k = 0; k < R1 * N_LAYER; ++k) p[k] += __shfl_xor(p[k], off, 64);
#pragma unroll
    for (int i = 1; i < N_LAYER; ++i) e[i] += __shfl_xor(e[i], off, 64);
  }

  // ---- per-row scalar recurrence; lane 0 stores A (8 x 4B, negligible) ----
  if (lane == 0) {
#pragma unroll
    for (int r = 0; r < R1; ++r) {
      float A = 1.f;
#pragma unroll
      for (int i = 0; i < N_LAYER; ++i)
        A += A * p[r * N_LAYER + i] + e[i];
      A_out[row0 + r] = A;
    }
  }
}

__global__ __launch_bounds__(256) void crossnet_phase2(
    const float* __restrict__ x,
    const float* __restrict__ A_in,
    const float* __restrict__ csum_in,
    float* __restrict__ out,
    int n_q) {  // n_q = n_rows * 256 float4s
  const float4* xq = (const float4*)x;
  const float4* cq = (const float4*)csum_in;
  float4* oq = (float4*)out;

  const int stride = gridDim.x * 256;
  for (int q = blockIdx.x * 256 + threadIdx.x; q < n_q; q += stride) {
    const float a = A_in[q >> 8];      // wave-uniform (64 lanes within one row)
    const float4 xv = xq[q];           // L3-hot: just streamed by phase 1
    const float4 c = cq[q & 255];      // L1-hot after first iteration
    float4 o;
    o.x = fmaf(xv.x, a, c.x);
    o.y = fmaf(xv.y, a, c.y);
    o.z = fmaf(xv.z, a, c.z);
    o.w = fmaf(xv.w, a, c.w);
    oq[q] = o;
  }
}

extern "C" void kernel_launch(void* const* d_in, const int* in_sizes, int n_in,
                              void* d_out, int out_size, void* d_ws, size_t ws_size,
                              hipStream_t stream) {
  const float* x = (const float*)d_in[0];
  const float* ww = (const float*)d_in[1];
  const float* wb = (const float*)d_in[2];
  float* out = (float*)d_out;

  const int n_rows = in_sizes[0] / N_FEAT;  // 16384
  float* A_ws = (float*)d_ws;               // n_rows floats
  float* csum_ws = A_ws + n_rows;           // N_FEAT floats (ws >= 68 KB)

  // Phase 1: 4 waves x R1 rows per block.
  const int rows_per_block = 4 * R1;        // 32
  const int n_blocks1 = (n_rows + rows_per_block - 1) / rows_per_block;  // 512
  crossnet_phase1<<<n_blocks1, 256, 0, stream>>>(x, ww, wb, A_ws, csum_ws, n_rows);

  // Phase 2: pure elementwise stream over n_rows*256 float4s.
  const int n_q = n_rows * 256;
  crossnet_phase2<<<4096, 256, 0, stream>>>(x, A_ws, csum_ws, out, n_q);
}

// Round 3
// 128.605 us; speedup vs baseline: 1.0595x; 1.0302x over previous
//
#include <hip/hip_runtime.h>

#define N_FEAT 1024
#define N_LAYER 4
#define R 8  // rows per wave (keeps w/b amortization at round-0 level per byte)

// Algebra: xi = A_i*x0 + C_i, C_i = sum_{j<i} b_j (row-independent).
//   p_i = <x0,w_i>, e_i = <C_i,w_i>; A_{i+1} = A_i*(1+p_i) + e_i;
//   out = A_4*x0 + C_4.
//
// Column-split single pass: each wave owns 8 rows x 512 features (half row).
// 1024 blocks -> 4 blocks/CU -> 16 waves/CU (2x round-0 residency), the
// hypothesis being that 8 waves/CU left the read pipe idle during each
// wave's compute/shuffle phases (read BW stuck at 2.1 TB/s in both R0 and
// the two-pass phase1). x is NOT held across the reduction (saves 64+ VGPRs);
// the store phase re-reads x from L2/L3, which this CU streamed ~us earlier.
// The two half-waves of a row-group exchange 35 butterfly-reduced partials
// (32 p + 3 e) through LDS + one __syncthreads.
__global__ __launch_bounds__(256, 4) void crossnet_kernel(
    const float* __restrict__ x,
    const float* __restrict__ weight_w,
    const float* __restrict__ weight_b,
    float* __restrict__ out,
    int n_rows) {
  const int wave = threadIdx.x >> 6;   // 0..3
  const int lane = threadIdx.x & 63;
  const int rowgrp = wave >> 1;        // 0,1
  const int half = wave & 1;           // 0,1 (column half)
  const int row0 = blockIdx.x * (2 * R) + rowgrp * R;
  if (row0 >= n_rows) return;

  const float4* xq = (const float4*)x;  // row stride = 256 float4
  float4* oq = (float4*)out;

  float p[R * N_LAYER];
#pragma unroll
  for (int k = 0; k < R * N_LAYER; ++k) p[k] = 0.f;
  float e[N_LAYER] = {0.f, 0.f, 0.f, 0.f};
  float4 csum[2];

  // ---- dot phase over this wave's 2 column chunks (512 features) ----
#pragma unroll
  for (int lc = 0; lc < 2; ++lc) {
    const int col = (half * 2 + lc) * 64 + lane;  // float4 column index

    // issue the 8 HBM x-loads for this chunk first (independent)
    float4 xv[R];
#pragma unroll
    for (int r = 0; r < R; ++r)
      xv[r] = xq[(size_t)(row0 + r) * 256 + col];

    // w/b (L1/L2-hot, 32 KB total) + e/cum while x loads are in flight
    float4 w[N_LAYER];
#pragma unroll
    for (int i = 0; i < N_LAYER; ++i)
      w[i] = ((const float4*)(weight_w + i * N_FEAT))[col];

    float4 cum = make_float4(0.f, 0.f, 0.f, 0.f);
#pragma unroll
    for (int i = 0; i < N_LAYER; ++i) {
      if (i > 0)
        e[i] += cum.x * w[i].x + cum.y * w[i].y + cum.z * w[i].z + cum.w * w[i].w;
      const float4 b = ((const float4*)(weight_b + i * N_FEAT))[col];
      cum.x += b.x; cum.y += b.y; cum.z += b.z; cum.w += b.w;
    }
    csum[lc] = cum;  // C_4 restricted to this chunk

#pragma unroll
    for (int r = 0; r < R; ++r) {
#pragma unroll
      for (int i = 0; i < N_LAYER; ++i) {
        p[r * N_LAYER + i] += xv[r].x * w[i].x + xv[r].y * w[i].y +
                              xv[r].z * w[i].z + xv[r].w * w[i].w;
      }
    }
  }

  // ---- butterfly: 35 independent values, 6 steps ----
#pragma unroll
  for (int off = 32; off > 0; off >>= 1) {
#pragma unroll
    for (int k = 0; k < R * N_LAYER; ++k) p[k] += __shfl_xor(p[k], off, 64);
#pragma unroll
    for (int i = 1; i < N_LAYER; ++i) e[i] += __shfl_xor(e[i], off, 64);
  }

  // ---- exchange partials with the partner half-wave via LDS ----
  __shared__ float pe[4][36];
  if (lane == 0) {
#pragma unroll
    for (int k = 0; k < R * N_LAYER; ++k) pe[wave][k] = p[k];
#pragma unroll
    for (int i = 1; i < N_LAYER; ++i) pe[wave][32 + i] = e[i];
  }
  __syncthreads();
  const int partner = wave ^ 1;
  float pp[R * N_LAYER], ep[N_LAYER];
#pragma unroll
  for (int k = 0; k < R * N_LAYER; ++k) pp[k] = pe[partner][k];  // broadcast
  ep[0] = 0.f;
#pragma unroll
  for (int i = 1; i < N_LAYER; ++i) ep[i] = pe[partner][32 + i];

  // ---- per-row recurrence (redundant across lanes, ~64 FMAs) ----
  float A[R];
#pragma unroll
  for (int r = 0; r < R; ++r) {
    A[r] = 1.f;
#pragma unroll
    for (int i = 0; i < N_LAYER; ++i) {
      const float pt = p[r * N_LAYER + i] + pp[r * N_LAYER + i];
      const float et = e[i] + ep[i];
      A[r] += A[r] * pt + et;
    }
  }

  // ---- store phase: re-read x (L2/L3-hot), write out ----
#pragma unroll
  for (int lc = 0; lc < 2; ++lc) {
    const int col = (half * 2 + lc) * 64 + lane;
    float4 xv[R];
#pragma unroll
    for (int r = 0; r < R; ++r)
      xv[r] = xq[(size_t)(row0 + r) * 256 + col];
#pragma unroll
    for (int r = 0; r < R; ++r) {
      float4 o;
      o.x = fmaf(xv[r].x, A[r], csum[lc].x);
      o.y = fmaf(xv[r].y, A[r], csum[lc].y);
      o.z = fmaf(xv[r].z, A[r], csum[lc].z);
      o.w = fmaf(xv[r].w, A[r], csum[lc].w);
      oq[(size_t)(row0 + r) * 256 + col] = o;
    }
  }
}

extern "C" void kernel_launch(void* const* d_in, const int* in_sizes, int n_in,
                              void* d_out, int out_size, void* d_ws, size_t ws_size,
                              hipStream_t stream) {
  const float* x = (const float*)d_in[0];
  const float* ww = (const float*)d_in[1];
  const float* wb = (const float*)d_in[2];
  float* out = (float*)d_out;

  const int n_rows = in_sizes[0] / N_FEAT;          // 16384
  const int rows_per_block = 2 * R;                 // 2 row-groups x 8 rows
  const int n_blocks = (n_rows + rows_per_block - 1) / rows_per_block;  // 1024
  crossnet_kernel<<<n_blocks, 256, 0, stream>>>(x, ww, wb, out, n_rows);
}

// Round 4
// 116.574 us; speedup vs baseline: 1.1689x; 1.1032x over previous
//
#include <hip/hip_runtime.h>

#define N_FEAT 1024
#define N_LAYER 4
#define RPG 8              // rows per LDS group/tile (32 KB)
#define GPB 4              // groups per block (grid-stride)
#define AS1 __attribute__((address_space(1)))
#define AS3 __attribute__((address_space(3)))

// Algebra: xi = A_i*x0 + C_i, C_i = sum_{j<i} b_j (row-independent).
//   p_i = <x0,w_i>, e_i = <C_i,w_i>; A_{i+1} = A_i*(1+p_i) + e_i;
//   out = A_4*x0 + csum.
//
// Async-staged structure (m97 shape): every prior variant burst-loaded x into
// VGPRs then drained (time-avg in-flight ~1KB/wave -> read side stuck at
// ~2.1 TB/s). Here x streams into LDS via global_load_lds double-buffering:
// stage(group k+1) is issued BEFORE compute(group k), so ~32KB/block stays in
// flight across the whole compute+store phase. w/e/csum are hoisted once per
// kernel (row-independent; the R=2 per-group weight-reload mistake is gone).
// xv is held in regs from dot->store, so x is read from HBM exactly once.
__global__ __launch_bounds__(256) void crossnet_kernel(
    const float* __restrict__ x,
    const float* __restrict__ weight_w,
    const float* __restrict__ weight_b,
    float* __restrict__ out,
    int n_rows) {
  const int wave = threadIdx.x >> 6;   // 0..3
  const int lane = threadIdx.x & 63;

  __shared__ float buf[2][RPG * N_FEAT];   // 2 x 32 KB

  // ---- hoisted once per kernel: w frags, e, csum (all row-independent) ----
  float4 w[4][N_LAYER];
  float4 csum[4];
  float e[N_LAYER] = {0.f, 0.f, 0.f, 0.f};
#pragma unroll
  for (int c = 0; c < 4; ++c) {
#pragma unroll
    for (int i = 0; i < N_LAYER; ++i)
      w[c][i] = ((const float4*)(weight_w + i * N_FEAT))[c * 64 + lane];
    float4 cum = make_float4(0.f, 0.f, 0.f, 0.f);
#pragma unroll
    for (int i = 0; i < N_LAYER; ++i) {
      if (i > 0)
        e[i] += cum.x * w[c][i].x + cum.y * w[c][i].y +
                cum.z * w[c][i].z + cum.w * w[c][i].w;
      const float4 b = ((const float4*)(weight_b + i * N_FEAT))[c * 64 + lane];
      cum.x += b.x; cum.y += b.y; cum.z += b.z; cum.w += b.w;
    }
    csum[c] = cum;
  }
  // reduce e across the wave once (18 shuffles total, one-time)
#pragma unroll
  for (int off = 32; off > 0; off >>= 1)
#pragma unroll
    for (int i = 1; i < N_LAYER; ++i) e[i] += __shfl_xor(e[i], off, 64);

  const int g0 = blockIdx.x * GPB;  // first group index for this block
  if (g0 * RPG >= n_rows) return;

  // Stage one 8x1024 group into buf[bsel]. Wave w stages rows 2w..2w+1.
  // LDS dest is wave-uniform (HW adds lane*16); global src is per-lane.
  auto stage = [&](int bsel, int grow) {
#pragma unroll
    for (int j = 0; j < 8; ++j) {
      const float* gsrc = x + (size_t)(grow + 2 * wave + (j >> 2)) * N_FEAT +
                          ((j & 3) * 64 + lane) * 4;
      float* ldst = &buf[bsel][(wave * 8 + j) * 256];
      __builtin_amdgcn_global_load_lds((const AS1 unsigned int*)gsrc,
                                       (AS3 unsigned int*)ldst, 16, 0, 0);
    }
  };

  stage(0, g0 * RPG);
  __syncthreads();   // vmcnt(0): buf0 ready

#pragma unroll
  for (int t = 0; t < GPB; ++t) {
    const int grow = (g0 + t) * RPG;
    if (grow >= n_rows) break;

    // issue next group's staging first: stays in flight across compute+store
    if (t + 1 < GPB && grow + RPG < n_rows) stage((t + 1) & 1, grow + RPG);

    const float* B = buf[t & 1];

    // ---- dot phase: read this wave's 2 rows from LDS, hold xv in regs ----
    float4 xv[2][4];
    float p[2 * N_LAYER];
#pragma unroll
    for (int k = 0; k < 2 * N_LAYER; ++k) p[k] = 0.f;
#pragma unroll
    for (int r = 0; r < 2; ++r) {
#pragma unroll
      for (int c = 0; c < 4; ++c) {
        xv[r][c] = *(const float4*)&B[(wave * 2 + r) * N_FEAT +
                                      (c * 64 + lane) * 4];
#pragma unroll
        for (int i = 0; i < N_LAYER; ++i) {
          p[r * N_LAYER + i] += xv[r][c].x * w[c][i].x + xv[r][c].y * w[c][i].y +
                                xv[r][c].z * w[c][i].z + xv[r][c].w * w[c][i].w;
        }
      }
    }

    // ---- butterfly: 8 p-values, 6 steps ----
#pragma unroll
    for (int off = 32; off > 0; off >>= 1)
#pragma unroll
      for (int k = 0; k < 2 * N_LAYER; ++k) p[k] += __shfl_xor(p[k], off, 64);

    // ---- recurrence + store (xv still in regs: x read from HBM once) ----
#pragma unroll
    for (int r = 0; r < 2; ++r) {
      float A = 1.f;
#pragma unroll
      for (int i = 0; i < N_LAYER; ++i)
        A += A * p[r * N_LAYER + i] + e[i];
      const size_t row = grow + wave * 2 + r;
#pragma unroll
      for (int c = 0; c < 4; ++c) {
        float4 o;
        o.x = fmaf(xv[r][c].x, A, csum[c].x);
        o.y = fmaf(xv[r][c].y, A, csum[c].y);
        o.z = fmaf(xv[r][c].z, A, csum[c].z);
        o.w = fmaf(xv[r][c].w, A, csum[c].w);
        ((float4*)out)[row * 256 + c * 64 + lane] = o;
      }
    }

    __syncthreads();  // drain staging (and stores); swap buffers
  }
}

extern "C" void kernel_launch(void* const* d_in, const int* in_sizes, int n_in,
                              void* d_out, int out_size, void* d_ws, size_t ws_size,
                              hipStream_t stream) {
  const float* x = (const float*)d_in[0];
  const float* ww = (const float*)d_in[1];
  const float* wb = (const float*)d_in[2];
  float* out = (float*)d_out;

  const int n_rows = in_sizes[0] / N_FEAT;            // 16384
  const int rows_per_block = RPG * GPB;               // 32
  const int n_blocks = (n_rows + rows_per_block - 1) / rows_per_block;  // 512
  crossnet_kernel<<<n_blocks, 256, 0, stream>>>(x, ww, wb, out, n_rows);
}